// Round 1
// baseline (1463.886 us; speedup 1.0000x reference)
//
#include <hip/hip_runtime.h>
#include <hip/hip_bf16.h>

#define N_ROWS 50000
#define M_PAD  50048      // 391 * 128
#define IN_DIM 500
#define KPAD   512
#define HID    512
#define OUTD   256
#define NNB    20
#define NEDGE  1000000

typedef __bf16 bf16x8 __attribute__((ext_vector_type(8)));
typedef float  f32x4  __attribute__((ext_vector_type(4)));

__device__ inline void lds_cp16(const void* g, void* s) {
  __builtin_amdgcn_global_load_lds(
      (const __attribute__((address_space(1))) unsigned int*)g,
      (__attribute__((address_space(3))) unsigned int*)s, 16, 0, 0);
}

__device__ inline void split2(float v, __hip_bfloat16* hi, __hip_bfloat16* lo) {
  __hip_bfloat16 h = __float2bfloat16(v);
  *hi = h;
  *lo = __float2bfloat16(v - __bfloat162float(h));
}

// ---------- conversions ----------
__global__ void k_convX(const float* __restrict__ x, __hip_bfloat16* __restrict__ hi,
                        __hip_bfloat16* __restrict__ lo) {
  size_t idx = (size_t)blockIdx.x * blockDim.x + threadIdx.x;
  if (idx >= (size_t)M_PAD * KPAD) return;
  int r = (int)(idx >> 9), c = (int)(idx & 511);
  float v = (r < N_ROWS && c < IN_DIM) ? x[(size_t)r * IN_DIM + c] : 0.f;
  split2(v, &hi[idx], &lo[idx]);
}

// W [Kin][Nin] -> Wt hi/lo [Nin][KPAD] (transpose + zero-pad K)
__global__ void k_convW(const float* __restrict__ W, __hip_bfloat16* __restrict__ hi,
                        __hip_bfloat16* __restrict__ lo, int Kin, int Nin) {
  int idx = blockIdx.x * blockDim.x + threadIdx.x;
  if (idx >= Nin * KPAD) return;
  int j = idx >> 9, k = idx & 511;
  float v = (k < Kin) ? W[(size_t)k * Nin + j] : 0.f;
  split2(v, &hi[idx], &lo[idx]);
}

// ---------- split-bf16 GEMM: C[M][ldc] = A[M][K] * B^T[N][K] + bias ----------
__global__ __launch_bounds__(256) void k_gemm(
    const __hip_bfloat16* __restrict__ Ahi, const __hip_bfloat16* __restrict__ Alo,
    const __hip_bfloat16* __restrict__ Bhi, const __hip_bfloat16* __restrict__ Blo,
    const float* __restrict__ bias, float* __restrict__ C, int K, int ldc) {
  __shared__ alignas(16) __hip_bfloat16 sA[2][128][32];
  __shared__ alignas(16) __hip_bfloat16 sB[2][128][32];
  const int tid = threadIdx.x, l = tid & 63, w = tid >> 6;
  const int mb = blockIdx.x, nb = blockIdx.y;
  const int mh = (w >> 1) * 64, nh = (w & 1) * 64;
  const int lrow = l >> 2, lk8 = (l & 3) * 8;
  const int l15 = l & 15, kq = (l >> 4) * 8;
  f32x4 acc[4][4] = {};
  for (int ks = 0; ks < K; ks += 32) {
#pragma unroll
    for (int cc = 0; cc < 2; ++cc) {
      int chunk = w * 2 + cc;                    // 0..7, 16 rows (1 KB) each
      int r = chunk * 16 + lrow;
      size_t aoff = (size_t)(mb * 128 + r) * K + ks + lk8;
      size_t boff = (size_t)(nb * 128 + r) * K + ks + lk8;
      lds_cp16(Ahi + aoff, (char*)(&sA[0][0][0]) + chunk * 1024);
      lds_cp16(Alo + aoff, (char*)(&sA[1][0][0]) + chunk * 1024);
      lds_cp16(Bhi + boff, (char*)(&sB[0][0][0]) + chunk * 1024);
      lds_cp16(Blo + boff, (char*)(&sB[1][0][0]) + chunk * 1024);
    }
    __syncthreads();   // drains vmcnt for global_load_lds
    bf16x8 ah[4], al[4];
#pragma unroll
    for (int m = 0; m < 4; ++m) {
      ah[m] = *(const bf16x8*)&sA[0][mh + m * 16 + l15][kq];
      al[m] = *(const bf16x8*)&sA[1][mh + m * 16 + l15][kq];
    }
#pragma unroll
    for (int n = 0; n < 4; ++n) {
      bf16x8 bh = *(const bf16x8*)&sB[0][nh + n * 16 + l15][kq];
      bf16x8 bl = *(const bf16x8*)&sB[1][nh + n * 16 + l15][kq];
#pragma unroll
      for (int m = 0; m < 4; ++m) {
        acc[m][n] = __builtin_amdgcn_mfma_f32_16x16x32_bf16(ah[m], bh, acc[m][n], 0, 0, 0);
        acc[m][n] = __builtin_amdgcn_mfma_f32_16x16x32_bf16(ah[m], bl, acc[m][n], 0, 0, 0);
        acc[m][n] = __builtin_amdgcn_mfma_f32_16x16x32_bf16(al[m], bh, acc[m][n], 0, 0, 0);
      }
    }
    __syncthreads();
  }
#pragma unroll
  for (int n = 0; n < 4; ++n) {
    int col = nb * 128 + nh + n * 16 + l15;
    float bv = bias[col];
#pragma unroll
    for (int m = 0; m < 4; ++m) {
      int row0 = mb * 128 + mh + m * 16 + (l >> 4) * 4;
#pragma unroll
      for (int r = 0; r < 4; ++r)
        C[(size_t)(row0 + r) * ldc + col] = acc[m][n][r] + bv;
    }
  }
}

// ---------- BN stats / params / apply ----------
__global__ void k_stats(const float* __restrict__ A, float* __restrict__ s1,
                        float* __restrict__ s2, int C) {
  int col = blockIdx.x * 256 + threadIdx.x;
  int r0 = blockIdx.y * 250;
  float a = 0.f, b = 0.f;
  for (int r = 0; r < 250; ++r) {
    float v = A[(size_t)(r0 + r) * C + col];
    a += v; b += v * v;
  }
  atomicAdd(&s1[col], a);
  atomicAdd(&s2[col], b);
}

__global__ void k_bnparam(const float* __restrict__ s1, const float* __restrict__ s2,
                          const float* __restrict__ gamma, const float* __restrict__ beta,
                          float* __restrict__ scale, float* __restrict__ shift, int C) {
  int i = blockIdx.x * blockDim.x + threadIdx.x;
  if (i >= C) return;
  float mu = s1[i] * (1.f / N_ROWS);
  float var = s2[i] * (1.f / N_ROWS) - mu * mu;
  float sc = gamma[i] / sqrtf(var + 1e-5f);
  scale[i] = sc;
  shift[i] = beta[i] - mu * sc;
}

__global__ void k_apply1(const float* __restrict__ h1, const float* __restrict__ scale,
                         const float* __restrict__ shift, __hip_bfloat16* __restrict__ hi,
                         __hip_bfloat16* __restrict__ lo) {
  size_t idx = (size_t)blockIdx.x * blockDim.x + threadIdx.x;
  if (idx >= (size_t)M_PAD * HID) return;
  int c = (int)(idx & 511);
  float v = h1[idx] * scale[c] + shift[c];
  split2(v, &hi[idx], &lo[idx]);
}

// BN2 + per-capsule l2norm -> xn (one 256-thread block per row)
__global__ __launch_bounds__(256) void k_bn2l2(const float* __restrict__ h2,
    const float* __restrict__ scale, const float* __restrict__ shift,
    float* __restrict__ xn) {
  int i = blockIdx.x, t = threadIdx.x;
  float v = h2[(size_t)i * OUTD + t] * scale[t] + shift[t];
  float ss = v * v;
  ss += __shfl_xor(ss, 1);  ss += __shfl_xor(ss, 2);  ss += __shfl_xor(ss, 4);
  ss += __shfl_xor(ss, 8);  ss += __shfl_xor(ss, 16);         // 32-dim capsule sum
  float inv = 1.f / fmaxf(sqrtf(ss), 1e-12f);
  xn[(size_t)i * OUTD + t] = v * inv;
}

// ---------- capsule routing: one wave per row ----------
__device__ inline void capnorm(f32x4& u) {
  float ss = u[0]*u[0] + u[1]*u[1] + u[2]*u[2] + u[3]*u[3];
  ss += __shfl_xor(ss, 1);  ss += __shfl_xor(ss, 2);  ss += __shfl_xor(ss, 4);
  float inv = 1.f / fmaxf(sqrtf(ss), 1e-12f);
  u *= inv;
}

template <int FINAL>
__global__ __launch_bounds__(128) void k_route(const float* __restrict__ xin,
    const int* __restrict__ nbrs, const float* __restrict__ dinv,
    float* __restrict__ xout) {
  __shared__ alignas(16) float zl[2][NNB * 256];
  int tid = threadIdx.x, w = tid >> 6, l = tid & 63;
  int row = blockIdx.x * 2 + w;
  float* zw = zl[w];
  const f32x4* xi4 = (const f32x4*)xin;
  f32x4 xc = xi4[(size_t)row * 64 + l];
  f32x4 sum = {0.f, 0.f, 0.f, 0.f};
  const int* nbp = nbrs + row * NNB;
  for (int m = 0; m < NNB; ++m) {
    int c = nbp[m];
    f32x4 zv = xi4[(size_t)c * 64 + l];
    *(f32x4*)&zw[(m * 64 + l) * 4] = zv;
    sum += zv;
  }
  f32x4 u = 0.125f * sum + xc;   // it=0: p = 1/k
  capnorm(u);
#pragma unroll
  for (int it = 1; it < 3; ++it) {
    f32x4 un = xc;
    for (int m = 0; m < NNB; ++m) {
      f32x4 z = *(const f32x4*)&zw[(m * 64 + l) * 4];
      float d = z[0]*u[0] + z[1]*u[1] + z[2]*u[2] + z[3]*u[3];
      d += __shfl_xor(d, 1);  d += __shfl_xor(d, 2);  d += __shfl_xor(d, 4);  // capsule dot
      float mx = d;
      mx = fmaxf(mx, __shfl_xor(mx, 8));
      mx = fmaxf(mx, __shfl_xor(mx, 16));
      mx = fmaxf(mx, __shfl_xor(mx, 32));                                     // max over caps
      float e = __expf(d - mx);
      float den = e;
      den += __shfl_xor(den, 8);  den += __shfl_xor(den, 16);  den += __shfl_xor(den, 32);
      float p = __fdividef(e, den);
      un += p * z;
    }
    if (it == 1) capnorm(un);
    u = un;
  }
  if (FINAL) u *= dinv[row];
  else       capnorm(u);
  *(f32x4*)(xout + (size_t)row * 256 + l * 4) = u;
}

// ---------- GCN graph prep + aggregation ----------
__global__ void k_deg(const int* __restrict__ e, int* __restrict__ rowcnt,
                      int* __restrict__ degc) {
  int i = blockIdx.x * blockDim.x + threadIdx.x;
  if (i >= NEDGE) return;
  atomicAdd(&rowcnt[e[i]], 1);
  atomicAdd(&degc[e[NEDGE + i]], 1);
}

__global__ void k_dinv(const int* __restrict__ degc, float* __restrict__ dinv) {
  int i = blockIdx.x * blockDim.x + threadIdx.x;
  if (i >= N_ROWS) return;
  dinv[i] = 1.f / sqrtf((float)(degc[i] + 1));   // +1 self loop
}

__global__ __launch_bounds__(1024) void k_scan(const int* __restrict__ rowcnt,
                                               int* __restrict__ rowptr) {
  __shared__ int s[1024];
  int tid = threadIdx.x;
  int carry = 0;
  for (int base = 0; base < 50176; base += 1024) {
    int i = base + tid;
    int v = (i < N_ROWS) ? rowcnt[i] : 0;
    s[tid] = v;
    __syncthreads();
    for (int off = 1; off < 1024; off <<= 1) {
      int t = (tid >= off) ? s[tid - off] : 0;
      __syncthreads();
      s[tid] += t;
      __syncthreads();
    }
    if (i <= N_ROWS) rowptr[i] = s[tid] - v + carry;   // exclusive
    carry += s[1023];
    __syncthreads();
  }
}

__global__ void k_fill(const int* __restrict__ e, const int* __restrict__ rowptr,
                       int* __restrict__ fill, int* __restrict__ colidx) {
  int i = blockIdx.x * blockDim.x + threadIdx.x;
  if (i >= NEDGE) return;
  int r = e[i];
  int pos = rowptr[r] + atomicAdd(&fill[r], 1);
  colidx[pos] = e[NEDGE + i];
}

__global__ __launch_bounds__(256) void k_agg(const float* __restrict__ Y,
    const int* __restrict__ rowptr, const int* __restrict__ colidx,
    const float* __restrict__ dinv, float* __restrict__ out) {
  int tid = threadIdx.x, w = tid >> 6, l = tid & 63;
  int row = blockIdx.x * 4 + w;
  const f32x4* Y4 = (const f32x4*)Y;
  f32x4 acc = Y4[(size_t)row * 64 + l];            // self loop: Y[i]
  int e0 = rowptr[row], e1 = rowptr[row + 1];
  for (int e = e0; e < e1; ++e)
    acc += Y4[(size_t)colidx[e] * 64 + l];
  acc *= dinv[row];
  *(f32x4*)(out + (size_t)row * 256 + l * 4) = acc;
}

extern "C" void kernel_launch(void* const* d_in, const int* in_sizes, int n_in,
                              void* d_out, int out_size, void* d_ws, size_t ws_size,
                              hipStream_t stream) {
  const float* x      = (const float*)d_in[0];
  const float* W1     = (const float*)d_in[1];
  const float* b1     = (const float*)d_in[2];
  const float* gamma1 = (const float*)d_in[3];
  const float* beta1  = (const float*)d_in[4];
  const float* W2     = (const float*)d_in[5];
  const float* b2     = (const float*)d_in[6];
  const float* gamma2 = (const float*)d_in[7];
  const float* beta2  = (const float*)d_in[8];
  const int* edges    = (const int*)d_in[9];
  const int* nbrs     = (const int*)d_in[10];

  char* ws = (char*)d_ws;
  size_t o = 0;
  auto take = [&](size_t b) -> char* { char* p = ws + o; o += (b + 255) & ~(size_t)255; return p; };

  __hip_bfloat16* xb_hi = (__hip_bfloat16*)take(51249152);   // [M_PAD][512] bf16
  __hip_bfloat16* xb_lo = (__hip_bfloat16*)take(51249152);
  float* h1             = (float*)take(102498304);           // [M_PAD][512] f32
  __hip_bfloat16* w1t_hi = (__hip_bfloat16*)take(524288);
  __hip_bfloat16* w1t_lo = (__hip_bfloat16*)take(524288);
  __hip_bfloat16* w2t_hi = (__hip_bfloat16*)take(262144);
  __hip_bfloat16* w2t_lo = (__hip_bfloat16*)take(262144);
  float* sums   = (float*)take(6144);   // s1a[512] s2a[512] s1b[256] s2b[256]
  float* params = (float*)take(6144);   // scale1[512] shift1[512] scale2[256] shift2[256]
  char* zero3 = take(600000);           // rowcnt, degc, fill (one memset)
  int* rowcnt = (int*)zero3;
  int* degc   = rowcnt + N_ROWS;
  int* fillc  = degc + N_ROWS;
  int* rowptr = (int*)take(200016);
  float* dinvp = (float*)take(200000);
  int* colidx  = (int*)take(4000000);

  float* s1a = sums,       *s2a = sums + 512,   *s1b = sums + 1024,   *s2b = sums + 1280;
  float* scale1 = params,  *shift1 = params + 512, *scale2 = params + 1024, *shift2 = params + 1280;

  // buffer reuse (sequential stream => safe):
  __hip_bfloat16* h1b_hi = xb_hi;        // after GEMM1, xb region is free
  __hip_bfloat16* h1b_lo = xb_lo;
  float* h2  = h1;                       // after apply1, h1 region is free (lower half)
  float* xn1 = (float*)((char*)h1 + 51249152);   // upper half of h1 region
  float* xn2 = (float*)xb_hi;            // after GEMM2, xb region free again
  float* Y   = h2;                       // after bn2l2, h2 free

  hipMemsetAsync(sums, 0, 6144, stream);
  hipMemsetAsync(zero3, 0, 600000, stream);

  k_convX<<<(M_PAD * KPAD + 255) / 256, 256, 0, stream>>>(x, xb_hi, xb_lo);
  k_convW<<<(HID * KPAD + 255) / 256, 256, 0, stream>>>(W1, w1t_hi, w1t_lo, IN_DIM, HID);
  k_convW<<<(OUTD * KPAD + 255) / 256, 256, 0, stream>>>(W2, w2t_hi, w2t_lo, HID, OUTD);
  k_deg<<<(NEDGE + 255) / 256, 256, 0, stream>>>(edges, rowcnt, degc);

  k_gemm<<<dim3(391, 4), 256, 0, stream>>>(xb_hi, xb_lo, w1t_hi, w1t_lo, b1, h1, KPAD, HID);
  k_stats<<<dim3(2, 200), 256, 0, stream>>>(h1, s1a, s2a, HID);
  k_bnparam<<<1, 512, 0, stream>>>(s1a, s2a, gamma1, beta1, scale1, shift1, HID);
  k_apply1<<<(M_PAD * HID + 255) / 256, 256, 0, stream>>>(h1, scale1, shift1, h1b_hi, h1b_lo);
  k_gemm<<<dim3(391, 2), 256, 0, stream>>>(h1b_hi, h1b_lo, w2t_hi, w2t_lo, b2, h2, KPAD, OUTD);
  k_stats<<<dim3(1, 200), 256, 0, stream>>>(h2, s1b, s2b, OUTD);
  k_bnparam<<<1, 256, 0, stream>>>(s1b, s2b, gamma2, beta2, scale2, shift2, OUTD);
  k_bn2l2<<<N_ROWS, 256, 0, stream>>>(h2, scale2, shift2, xn1);

  k_scan<<<1, 1024, 0, stream>>>(rowcnt, rowptr);
  k_dinv<<<(N_ROWS + 255) / 256, 256, 0, stream>>>(degc, dinvp);
  k_fill<<<(NEDGE + 255) / 256, 256, 0, stream>>>(edges, rowptr, fillc, colidx);

  k_route<0><<<25000, 128, 0, stream>>>(xn1, nbrs, dinvp, xn2);
  k_route<1><<<25000, 128, 0, stream>>>(xn2, nbrs, dinvp, Y);
  k_agg<<<12500, 256, 0, stream>>>(Y, rowptr, colidx, dinvp, (float*)d_out);
}

// Round 2
// 1156.144 us; speedup vs baseline: 1.2662x; 1.2662x over previous
//
#include <hip/hip_runtime.h>
#include <hip/hip_bf16.h>

#define N_ROWS 50000
#define M_PAD  50048      // 391 * 128
#define IN_DIM 500
#define KPAD   512
#define HID    512
#define OUTD   256
#define NNB    20
#define NEDGE  1000000

typedef __bf16 bf16x8 __attribute__((ext_vector_type(8)));
typedef float  f32x4  __attribute__((ext_vector_type(4)));

__device__ inline void lds_cp16(const void* g, void* s) {
  __builtin_amdgcn_global_load_lds(
      (const __attribute__((address_space(1))) unsigned int*)g,
      (__attribute__((address_space(3))) unsigned int*)s, 16, 0, 0);
}

__device__ inline void split2(float v, __hip_bfloat16* hi, __hip_bfloat16* lo) {
  __hip_bfloat16 h = __float2bfloat16(v);
  *hi = h;
  *lo = __float2bfloat16(v - __bfloat162float(h));
}

// ---------- conversions ----------
__global__ void k_convX(const float* __restrict__ x, __hip_bfloat16* __restrict__ hi,
                        __hip_bfloat16* __restrict__ lo) {
  size_t idx = (size_t)blockIdx.x * blockDim.x + threadIdx.x;
  if (idx >= (size_t)M_PAD * KPAD) return;
  int r = (int)(idx >> 9), c = (int)(idx & 511);
  float v = (r < N_ROWS && c < IN_DIM) ? x[(size_t)r * IN_DIM + c] : 0.f;
  split2(v, &hi[idx], &lo[idx]);
}

// W [Kin][Nin] -> Wt hi/lo [Nin][KPAD] (transpose + zero-pad K)
__global__ void k_convW(const float* __restrict__ W, __hip_bfloat16* __restrict__ hi,
                        __hip_bfloat16* __restrict__ lo, int Kin, int Nin) {
  int idx = blockIdx.x * blockDim.x + threadIdx.x;
  if (idx >= Nin * KPAD) return;
  int j = idx >> 9, k = idx & 511;
  float v = (k < Kin) ? W[(size_t)k * Nin + j] : 0.f;
  split2(v, &hi[idx], &lo[idx]);
}

// ---------- split-bf16 GEMM: C[M][ldc] = A[M][K] * B^T[N][K] + bias ----------
__global__ __launch_bounds__(256) void k_gemm(
    const __hip_bfloat16* __restrict__ Ahi, const __hip_bfloat16* __restrict__ Alo,
    const __hip_bfloat16* __restrict__ Bhi, const __hip_bfloat16* __restrict__ Blo,
    const float* __restrict__ bias, float* __restrict__ C, int K, int ldc) {
  __shared__ alignas(16) __hip_bfloat16 sA[2][128][32];
  __shared__ alignas(16) __hip_bfloat16 sB[2][128][32];
  const int tid = threadIdx.x, l = tid & 63, w = tid >> 6;
  const int mb = blockIdx.x, nb = blockIdx.y;
  const int mh = (w >> 1) * 64, nh = (w & 1) * 64;
  const int lrow = l >> 2, lk8 = (l & 3) * 8;
  const int l15 = l & 15, kq = (l >> 4) * 8;
  f32x4 acc[4][4] = {};
  for (int ks = 0; ks < K; ks += 32) {
#pragma unroll
    for (int cc = 0; cc < 2; ++cc) {
      int chunk = w * 2 + cc;                    // 0..7, 16 rows (1 KB) each
      int r = chunk * 16 + lrow;
      size_t aoff = (size_t)(mb * 128 + r) * K + ks + lk8;
      size_t boff = (size_t)(nb * 128 + r) * K + ks + lk8;
      lds_cp16(Ahi + aoff, (char*)(&sA[0][0][0]) + chunk * 1024);
      lds_cp16(Alo + aoff, (char*)(&sA[1][0][0]) + chunk * 1024);
      lds_cp16(Bhi + boff, (char*)(&sB[0][0][0]) + chunk * 1024);
      lds_cp16(Blo + boff, (char*)(&sB[1][0][0]) + chunk * 1024);
    }
    __syncthreads();   // drains vmcnt for global_load_lds
    bf16x8 ah[4], al[4];
#pragma unroll
    for (int m = 0; m < 4; ++m) {
      ah[m] = *(const bf16x8*)&sA[0][mh + m * 16 + l15][kq];
      al[m] = *(const bf16x8*)&sA[1][mh + m * 16 + l15][kq];
    }
#pragma unroll
    for (int n = 0; n < 4; ++n) {
      bf16x8 bh = *(const bf16x8*)&sB[0][nh + n * 16 + l15][kq];
      bf16x8 bl = *(const bf16x8*)&sB[1][nh + n * 16 + l15][kq];
#pragma unroll
      for (int m = 0; m < 4; ++m) {
        acc[m][n] = __builtin_amdgcn_mfma_f32_16x16x32_bf16(ah[m], bh, acc[m][n], 0, 0, 0);
        acc[m][n] = __builtin_amdgcn_mfma_f32_16x16x32_bf16(ah[m], bl, acc[m][n], 0, 0, 0);
        acc[m][n] = __builtin_amdgcn_mfma_f32_16x16x32_bf16(al[m], bh, acc[m][n], 0, 0, 0);
      }
    }
    __syncthreads();
  }
#pragma unroll
  for (int n = 0; n < 4; ++n) {
    int col = nb * 128 + nh + n * 16 + l15;
    float bv = bias[col];
#pragma unroll
    for (int m = 0; m < 4; ++m) {
      int row0 = mb * 128 + mh + m * 16 + (l >> 4) * 4;
#pragma unroll
      for (int r = 0; r < 4; ++r)
        C[(size_t)(row0 + r) * ldc + col] = acc[m][n][r] + bv;
    }
  }
}

// ---------- BN stats / params / apply ----------
__global__ void k_stats(const float* __restrict__ A, float* __restrict__ s1,
                        float* __restrict__ s2, int C) {
  int col = blockIdx.x * 256 + threadIdx.x;
  int r0 = blockIdx.y * 250;
  float a = 0.f, b = 0.f;
  for (int r = 0; r < 250; ++r) {
    float v = A[(size_t)(r0 + r) * C + col];
    a += v; b += v * v;
  }
  atomicAdd(&s1[col], a);
  atomicAdd(&s2[col], b);
}

__global__ void k_bnparam(const float* __restrict__ s1, const float* __restrict__ s2,
                          const float* __restrict__ gamma, const float* __restrict__ beta,
                          float* __restrict__ scale, float* __restrict__ shift, int C) {
  int i = blockIdx.x * blockDim.x + threadIdx.x;
  if (i >= C) return;
  float mu = s1[i] * (1.f / N_ROWS);
  float var = s2[i] * (1.f / N_ROWS) - mu * mu;
  float sc = gamma[i] / sqrtf(var + 1e-5f);
  scale[i] = sc;
  shift[i] = beta[i] - mu * sc;
}

__global__ void k_apply1(const float* __restrict__ h1, const float* __restrict__ scale,
                         const float* __restrict__ shift, __hip_bfloat16* __restrict__ hi,
                         __hip_bfloat16* __restrict__ lo) {
  size_t idx = (size_t)blockIdx.x * blockDim.x + threadIdx.x;
  if (idx >= (size_t)M_PAD * HID) return;
  int c = (int)(idx & 511);
  float v = h1[idx] * scale[c] + shift[c];
  split2(v, &hi[idx], &lo[idx]);
}

// BN2 + per-capsule l2norm -> xn (one 256-thread block per row)
__global__ __launch_bounds__(256) void k_bn2l2(const float* __restrict__ h2,
    const float* __restrict__ scale, const float* __restrict__ shift,
    float* __restrict__ xn) {
  int i = blockIdx.x, t = threadIdx.x;
  float v = h2[(size_t)i * OUTD + t] * scale[t] + shift[t];
  float ss = v * v;
  ss += __shfl_xor(ss, 1);  ss += __shfl_xor(ss, 2);  ss += __shfl_xor(ss, 4);
  ss += __shfl_xor(ss, 8);  ss += __shfl_xor(ss, 16);         // 32-dim capsule sum
  float inv = 1.f / fmaxf(sqrtf(ss), 1e-12f);
  xn[(size_t)i * OUTD + t] = v * inv;
}

// ---------- capsule routing: one wave per row, z in registers ----------
__device__ inline void capnorm(f32x4& u) {
  float ss = u[0]*u[0] + u[1]*u[1] + u[2]*u[2] + u[3]*u[3];
  ss += __shfl_xor(ss, 1);  ss += __shfl_xor(ss, 2);  ss += __shfl_xor(ss, 4);
  float inv = 1.f / fmaxf(sqrtf(ss), 1e-12f);
  u *= inv;
}

template <int FINAL>
__global__ __launch_bounds__(256, 3) void k_route(const float* __restrict__ xin,
    const int* __restrict__ nbrs, const float* __restrict__ dinv,
    float* __restrict__ xout) {
  int tid = threadIdx.x, w = tid >> 6, l = tid & 63;
  int row = blockIdx.x * 4 + w;
  const f32x4* xi4 = (const f32x4*)xin;
  const int* nbp = nbrs + row * NNB;
  int c[NNB];
#pragma unroll
  for (int m = 0; m < NNB; ++m) c[m] = nbp[m];
  f32x4 xc = xi4[(size_t)row * 64 + l];
  f32x4 z[NNB];
  f32x4 sum = {0.f, 0.f, 0.f, 0.f};
#pragma unroll
  for (int m = 0; m < NNB; ++m) z[m] = xi4[(size_t)c[m] * 64 + l];
#pragma unroll
  for (int m = 0; m < NNB; ++m) sum += z[m];
  f32x4 u = 0.125f * sum + xc;   // it=0: p = 1/k (softmax of zeros)
  capnorm(u);
#pragma unroll
  for (int it = 1; it < 3; ++it) {
    f32x4 un = xc;
#pragma unroll
    for (int m = 0; m < NNB; ++m) {
      f32x4 z_ = z[m];
      float d = z_[0]*u[0] + z_[1]*u[1] + z_[2]*u[2] + z_[3]*u[3];
      d += __shfl_xor(d, 1);  d += __shfl_xor(d, 2);  d += __shfl_xor(d, 4);  // capsule dot
      // |d| <= 1 (both operands capsule-l2-normalized) -> no max subtraction needed
      float e = __expf(d);
      float den = e;
      den += __shfl_xor(den, 8);  den += __shfl_xor(den, 16);  den += __shfl_xor(den, 32);
      float p = __fdividef(e, den);
      un += p * z_;
    }
    if (it == 1) capnorm(un);
    u = un;
  }
  if (FINAL) u *= dinv[row];
  else       capnorm(u);
  *(f32x4*)(xout + (size_t)row * 256 + l * 4) = u;
}

// ---------- GCN graph prep + aggregation ----------
__global__ void k_deg(const int* __restrict__ e, int* __restrict__ rowcnt,
                      int* __restrict__ degc) {
  int i = blockIdx.x * blockDim.x + threadIdx.x;
  if (i >= NEDGE) return;
  atomicAdd(&rowcnt[e[i]], 1);
  atomicAdd(&degc[e[NEDGE + i]], 1);
}

__global__ void k_dinv(const int* __restrict__ degc, float* __restrict__ dinv) {
  int i = blockIdx.x * blockDim.x + threadIdx.x;
  if (i >= N_ROWS) return;
  dinv[i] = 1.f / sqrtf((float)(degc[i] + 1));   // +1 self loop
}

__global__ __launch_bounds__(1024) void k_scan(const int* __restrict__ rowcnt,
                                               int* __restrict__ rowptr) {
  __shared__ int s[1024];
  int tid = threadIdx.x;
  int carry = 0;
  for (int base = 0; base < 50176; base += 1024) {
    int i = base + tid;
    int v = (i < N_ROWS) ? rowcnt[i] : 0;
    s[tid] = v;
    __syncthreads();
    for (int off = 1; off < 1024; off <<= 1) {
      int t = (tid >= off) ? s[tid - off] : 0;
      __syncthreads();
      s[tid] += t;
      __syncthreads();
    }
    if (i <= N_ROWS) rowptr[i] = s[tid] - v + carry;   // exclusive
    carry += s[1023];
    __syncthreads();
  }
}

__global__ void k_fill(const int* __restrict__ e, const int* __restrict__ rowptr,
                       int* __restrict__ fill, int* __restrict__ colidx) {
  int i = blockIdx.x * blockDim.x + threadIdx.x;
  if (i >= NEDGE) return;
  int r = e[i];
  int pos = rowptr[r] + atomicAdd(&fill[r], 1);
  colidx[pos] = e[NEDGE + i];
}

__global__ __launch_bounds__(256) void k_agg(const float* __restrict__ Y,
    const int* __restrict__ rowptr, const int* __restrict__ colidx,
    const float* __restrict__ dinv, float* __restrict__ out) {
  int tid = threadIdx.x, w = tid >> 6, l = tid & 63;
  int row = blockIdx.x * 4 + w;
  const f32x4* Y4 = (const f32x4*)Y;
  f32x4 a0 = Y4[(size_t)row * 64 + l];            // self loop: Y[i]
  f32x4 a1 = {0,0,0,0}, a2 = {0,0,0,0}, a3 = {0,0,0,0};
  int e0 = rowptr[row], e1 = rowptr[row + 1];
  int e = e0;
  for (; e + 4 <= e1; e += 4) {
    int c0 = colidx[e], c1 = colidx[e+1], c2 = colidx[e+2], c3 = colidx[e+3];
    a0 += Y4[(size_t)c0 * 64 + l];
    a1 += Y4[(size_t)c1 * 64 + l];
    a2 += Y4[(size_t)c2 * 64 + l];
    a3 += Y4[(size_t)c3 * 64 + l];
  }
  for (; e < e1; ++e) a1 += Y4[(size_t)colidx[e] * 64 + l];
  f32x4 acc = (a0 + a1) + (a2 + a3);
  acc *= dinv[row];
  *(f32x4*)(out + (size_t)row * 256 + l * 4) = acc;
}

extern "C" void kernel_launch(void* const* d_in, const int* in_sizes, int n_in,
                              void* d_out, int out_size, void* d_ws, size_t ws_size,
                              hipStream_t stream) {
  const float* x      = (const float*)d_in[0];
  const float* W1     = (const float*)d_in[1];
  const float* b1     = (const float*)d_in[2];
  const float* gamma1 = (const float*)d_in[3];
  const float* beta1  = (const float*)d_in[4];
  const float* W2     = (const float*)d_in[5];
  const float* b2     = (const float*)d_in[6];
  const float* gamma2 = (const float*)d_in[7];
  const float* beta2  = (const float*)d_in[8];
  const int* edges    = (const int*)d_in[9];
  const int* nbrs     = (const int*)d_in[10];

  char* ws = (char*)d_ws;
  size_t o = 0;
  auto take = [&](size_t b) -> char* { char* p = ws + o; o += (b + 255) & ~(size_t)255; return p; };

  __hip_bfloat16* xb_hi = (__hip_bfloat16*)take(51249152);   // [M_PAD][512] bf16
  __hip_bfloat16* xb_lo = (__hip_bfloat16*)take(51249152);
  float* h1             = (float*)take(102498304);           // [M_PAD][512] f32
  __hip_bfloat16* w1t_hi = (__hip_bfloat16*)take(524288);
  __hip_bfloat16* w1t_lo = (__hip_bfloat16*)take(524288);
  __hip_bfloat16* w2t_hi = (__hip_bfloat16*)take(262144);
  __hip_bfloat16* w2t_lo = (__hip_bfloat16*)take(262144);
  float* sums   = (float*)take(6144);   // s1a[512] s2a[512] s1b[256] s2b[256]
  float* params = (float*)take(6144);   // scale1[512] shift1[512] scale2[256] shift2[256]
  char* zero3 = take(600000);           // rowcnt, degc, fill (one memset)
  int* rowcnt = (int*)zero3;
  int* degc   = rowcnt + N_ROWS;
  int* fillc  = degc + N_ROWS;
  int* rowptr = (int*)take(200016);
  float* dinvp = (float*)take(200000);
  int* colidx  = (int*)take(4000000);

  float* s1a = sums,       *s2a = sums + 512,   *s1b = sums + 1024,   *s2b = sums + 1280;
  float* scale1 = params,  *shift1 = params + 512, *scale2 = params + 1024, *shift2 = params + 1280;

  // buffer reuse (sequential stream => safe):
  __hip_bfloat16* h1b_hi = xb_hi;        // after GEMM1, xb region is free
  __hip_bfloat16* h1b_lo = xb_lo;
  float* h2  = h1;                       // after apply1, h1 region is free (lower half)
  float* xn1 = (float*)((char*)h1 + 51249152);   // upper half of h1 region
  float* xn2 = (float*)xb_hi;            // after GEMM2, xb region free again
  float* Y   = h2;                       // after bn2l2, h2 free

  hipMemsetAsync(sums, 0, 6144, stream);
  hipMemsetAsync(zero3, 0, 600000, stream);

  k_convX<<<(M_PAD * KPAD + 255) / 256, 256, 0, stream>>>(x, xb_hi, xb_lo);
  k_convW<<<(HID * KPAD + 255) / 256, 256, 0, stream>>>(W1, w1t_hi, w1t_lo, IN_DIM, HID);
  k_convW<<<(OUTD * KPAD + 255) / 256, 256, 0, stream>>>(W2, w2t_hi, w2t_lo, HID, OUTD);
  k_deg<<<(NEDGE + 255) / 256, 256, 0, stream>>>(edges, rowcnt, degc);

  k_gemm<<<dim3(391, 4), 256, 0, stream>>>(xb_hi, xb_lo, w1t_hi, w1t_lo, b1, h1, KPAD, HID);
  k_stats<<<dim3(2, 200), 256, 0, stream>>>(h1, s1a, s2a, HID);
  k_bnparam<<<1, 512, 0, stream>>>(s1a, s2a, gamma1, beta1, scale1, shift1, HID);
  k_apply1<<<(M_PAD * HID + 255) / 256, 256, 0, stream>>>(h1, scale1, shift1, h1b_hi, h1b_lo);
  k_gemm<<<dim3(391, 2), 256, 0, stream>>>(h1b_hi, h1b_lo, w2t_hi, w2t_lo, b2, h2, KPAD, OUTD);
  k_stats<<<dim3(1, 200), 256, 0, stream>>>(h2, s1b, s2b, OUTD);
  k_bnparam<<<1, 256, 0, stream>>>(s1b, s2b, gamma2, beta2, scale2, shift2, OUTD);
  k_bn2l2<<<N_ROWS, 256, 0, stream>>>(h2, scale2, shift2, xn1);

  k_scan<<<1, 1024, 0, stream>>>(rowcnt, rowptr);
  k_dinv<<<(N_ROWS + 255) / 256, 256, 0, stream>>>(degc, dinvp);
  k_fill<<<(NEDGE + 255) / 256, 256, 0, stream>>>(edges, rowptr, fillc, colidx);

  k_route<0><<<12500, 256, 0, stream>>>(xn1, nbrs, dinvp, xn2);
  k_route<1><<<12500, 256, 0, stream>>>(xn2, nbrs, dinvp, Y);
  k_agg<<<12500, 256, 0, stream>>>(Y, rowptr, colidx, dinvp, (float*)d_out);
}